// Round 19
// baseline (3409.568 us; speedup 1.0000x reference)
//
#include <hip/hip_runtime.h>
#include <cstddef>
#include <cstdint>

#define NGRAPH 2048
#define NPG    32
#define EPG    64
#define NNODE  (NGRAPH*NPG)   // 65536
#define NEDGE  (NGRAPH*EPG)   // 131072
#define FINDIM 70
#define EINDIM 6
#define HID    128
#define NBLK   4
#define CAH    8
#define CAD    128
#define ES     68             // per-head e/k/q LDS stride (f32)
#define XS     132            // xnew/skip LDS stride inside el region

typedef __attribute__((ext_vector_type(8))) short bf16x8_t;
typedef __attribute__((ext_vector_type(4))) float f32x4;
typedef unsigned short ushortb;

#define MF3(accv, Ah_, Al_, Bh_, Bl_)                                          \
  accv = __builtin_amdgcn_mfma_f32_16x16x32_bf16(Ah_, Bh_, accv, 0, 0, 0);     \
  accv = __builtin_amdgcn_mfma_f32_16x16x32_bf16(Ah_, Bl_, accv, 0, 0, 0);     \
  accv = __builtin_amdgcn_mfma_f32_16x16x32_bf16(Al_, Bh_, accv, 0, 0, 0);

// dual-accumulator variant: accA gets the main product, accB the bf16x3
// correction terms -> two short independent chains instead of one 3-deep.
#define MF3D(accA, accB, Ah_, Al_, Bh_, Bl_)                                   \
  accA = __builtin_amdgcn_mfma_f32_16x16x32_bf16(Ah_, Bh_, accA, 0, 0, 0);     \
  accB = __builtin_amdgcn_mfma_f32_16x16x32_bf16(Ah_, Bl_, accB, 0, 0, 0);     \
  accB = __builtin_amdgcn_mfma_f32_16x16x32_bf16(Al_, Bh_, accB, 0, 0, 0);

__device__ inline void split8(const float* p, bf16x8_t& h, bf16x8_t& l) {
  float4 v0 = *(const float4*)p, v1 = *(const float4*)(p + 4);
  float vv[8] = {v0.x, v0.y, v0.z, v0.w, v1.x, v1.y, v1.z, v1.w};
#pragma unroll
  for (int j = 0; j < 8; j++) {
    unsigned u = __builtin_bit_cast(unsigned, vv[j]);
    h[j] = (short)(u >> 16);
    float r = vv[j] - __builtin_bit_cast(float, u & 0xFFFF0000u);
    l[j] = (short)(__builtin_bit_cast(unsigned, r) >> 16);
  }
}

// ---------------- generic tiled f32 GEMM (K=70 / K=6 embeds) -------------------------
template<bool BIAS, bool ELU>
__global__ __launch_bounds__(256) void gemm_kernel(
    const float* __restrict__ A, const float* __restrict__ W,
    const float* __restrict__ bias, float* __restrict__ C,
    int M, int K, int Nc) {
  __shared__ float As[8][64];
  __shared__ float Bs[8][65];
  const int bm = blockIdx.y * 64, bn = blockIdx.x * 64;
  const int tid = threadIdx.x;
  const int tr = tid >> 4, tc = tid & 15;
  float acc[4][4];
#pragma unroll
  for (int i = 0; i < 4; i++)
#pragma unroll
    for (int j = 0; j < 4; j++) acc[i][j] = 0.f;
  for (int k0 = 0; k0 < K; k0 += 8) {
#pragma unroll
    for (int l = 0; l < 2; l++) {
      int idx = tid + l * 256;
      int r = idx >> 3, c = idx & 7;
      As[c][r] = (k0 + c < K) ? A[(size_t)(bm + r) * K + k0 + c] : 0.f;
      int rw = idx >> 6, cw = idx & 63;
      Bs[rw][cw] = (k0 + rw < K) ? W[(size_t)(k0 + rw) * Nc + bn + cw] : 0.f;
    }
    __syncthreads();
#pragma unroll
    for (int kk = 0; kk < 8; kk++) {
      float a_[4], w_[4];
#pragma unroll
      for (int i = 0; i < 4; i++) a_[i] = As[kk][tr * 4 + i];
#pragma unroll
      for (int j = 0; j < 4; j++) w_[j] = Bs[kk][tc * 4 + j];
#pragma unroll
      for (int i = 0; i < 4; i++)
#pragma unroll
        for (int j = 0; j < 4; j++) acc[i][j] += a_[i] * w_[j];
    }
    __syncthreads();
  }
#pragma unroll
  for (int i = 0; i < 4; i++) {
    int r = bm + tr * 4 + i;
#pragma unroll
    for (int j = 0; j < 4; j++) {
      int c = bn + tc * 4 + j;
      float v = acc[i][j];
      if (BIAS) v += bias[c];
      if (ELU) v = v > 0.f ? v : expm1f(v);
      C[(size_t)r * Nc + c] = v;
    }
  }
}

static void run_gemm(const float* A, const float* W, const float* bias, float* C,
                     int M, int K, int Nc, bool eluf, hipStream_t st) {
  dim3 grid(Nc / 64, M / 64), block(256);
  if (eluf) gemm_kernel<true, true><<<grid, block, 0, st>>>(A, W, bias, C, M, K, Nc);
  else      gemm_kernel<true, false><<<grid, block, 0, st>>>(A, W, bias, C, M, K, Nc);
}

// ------- weight f32[B][K][N] -> transposed bf16 hi/lo, dest [b][dstN][K] @ nOff ------
__global__ void convw_kernel(const float* __restrict__ src, ushortb* __restrict__ h,
                             ushortb* __restrict__ l, int K, int N, int total,
                             int dstN, int nOff) {
  int idx = blockIdx.x * 256 + threadIdx.x;
  if (idx >= total) return;
  int k = idx % K;
  int t2 = idx / K;
  int n = t2 % N;
  int b = t2 / N;
  float v = src[((size_t)b * K + k) * N + n];
  unsigned uv = __builtin_bit_cast(unsigned, v);
  ushortb hb = (ushortb)(uv >> 16);
  float hf = __builtin_bit_cast(float, uv & 0xFFFF0000u);
  float rr = v - hf;
  ushortb lb = (ushortb)(__builtin_bit_cast(unsigned, rr) >> 16);
  size_t didx = ((size_t)b * dstN + nOff + n) * K + k;
  h[didx] = hb;
  l[didx] = lb;
}

// ---------------- concat q/k/v biases -> [8][384] ------------------------------------
__global__ void bcat_kernel(const float* __restrict__ bq, const float* __restrict__ bk,
                            const float* __restrict__ bv, float* __restrict__ o) {
  int t = blockIdx.x * 256 + threadIdx.x;
  if (t >= 8 * 384) return;
  int pi = t / 384, c = t % 384, sel = c >> 7, cc = c & 127;
  const float* s = sel == 0 ? bq : (sel == 1 ? bk : bv);
  o[t] = s[pi * 128 + cc];
}

// ---------------- 8-wave MFMA GEMM (BM=128, BN=128) — co-attention projections -------
__global__ __launch_bounds__(512) void gemm_mfma8_kernel(
    const float* __restrict__ A, const ushortb* __restrict__ Wh,
    const ushortb* __restrict__ Wl, float* __restrict__ C, int M, int K, int N) {
  __shared__ ushortb Ah[128 * 40];
  __shared__ ushortb Al[128 * 40];
  const int bm = blockIdx.y * 128, bn = blockIdx.x * 128;
  const int tid = threadIdx.x, lane = tid & 63, w = tid >> 6;
  const int wr = w >> 1, wc = w & 1;
  const int l16 = lane & 15, lk = lane >> 4;
  f32x4 acc[2][4];
#pragma unroll
  for (int m = 0; m < 2; m++)
#pragma unroll
    for (int n = 0; n < 4; n++) acc[m][n] = (f32x4)0.f;

  for (int k0 = 0; k0 < K; k0 += 32) {
    __syncthreads();
#pragma unroll
    for (int p = 0; p < 2; p++) {
      int base = p * 2048 + tid * 4;
      int r = base >> 5, c = base & 31;
      const float4 v = *(const float4*)(A + (size_t)(bm + r) * K + k0 + c);
      unsigned u0 = __builtin_bit_cast(unsigned, v.x);
      unsigned u1 = __builtin_bit_cast(unsigned, v.y);
      unsigned u2 = __builtin_bit_cast(unsigned, v.z);
      unsigned u3 = __builtin_bit_cast(unsigned, v.w);
      ushort4 hv;
      hv.x = (ushortb)(u0 >> 16); hv.y = (ushortb)(u1 >> 16);
      hv.z = (ushortb)(u2 >> 16); hv.w = (ushortb)(u3 >> 16);
      float r0 = v.x - __builtin_bit_cast(float, u0 & 0xFFFF0000u);
      float r1 = v.y - __builtin_bit_cast(float, u1 & 0xFFFF0000u);
      float r2 = v.z - __builtin_bit_cast(float, u2 & 0xFFFF0000u);
      float r3 = v.w - __builtin_bit_cast(float, u3 & 0xFFFF0000u);
      ushort4 lv;
      lv.x = (ushortb)(__builtin_bit_cast(unsigned, r0) >> 16);
      lv.y = (ushortb)(__builtin_bit_cast(unsigned, r1) >> 16);
      lv.z = (ushortb)(__builtin_bit_cast(unsigned, r2) >> 16);
      lv.w = (ushortb)(__builtin_bit_cast(unsigned, r3) >> 16);
      *(ushort4*)(&Ah[r * 40 + c]) = hv;
      *(ushort4*)(&Al[r * 40 + c]) = lv;
    }
    __syncthreads();
    bf16x8_t bh[4], bl[4];
#pragma unroll
    for (int n = 0; n < 4; n++) {
      size_t o = (size_t)(bn + wc * 64 + n * 16 + l16) * K + k0 + lk * 8;
      bh[n] = *(const bf16x8_t*)(Wh + o);
      bl[n] = *(const bf16x8_t*)(Wl + o);
    }
    bf16x8_t ah[2], al2[2];
#pragma unroll
    for (int m = 0; m < 2; m++) {
      int ao = (wr * 32 + m * 16 + l16) * 40 + lk * 8;
      ah[m]  = *(const bf16x8_t*)(&Ah[ao]);
      al2[m] = *(const bf16x8_t*)(&Al[ao]);
    }
#pragma unroll
    for (int m = 0; m < 2; m++)
#pragma unroll
      for (int n = 0; n < 4; n++) {
        MF3(acc[m][n], ah[m], al2[m], bh[n], bl[n]);
      }
  }
#pragma unroll
  for (int m = 0; m < 2; m++)
#pragma unroll
    for (int n = 0; n < 4; n++) {
      int col = bn + wc * 64 + n * 16 + l16;
#pragma unroll
      for (int r = 0; r < 4; r++) {
        int row = bm + wr * 32 + m * 16 + lk * 4 + r;
        C[(size_t)row * N + col] = acc[m][n][r];
      }
    }
}

static void run_mf8(const float* A, const ushortb* Wh, const ushortb* Wl,
                    float* C, int M, int K, int N, hipStream_t st) {
  dim3 grid(N / 128, M / 128), block(512);
  gemm_mfma8_kernel<<<grid, block, 0, st>>>(A, Wh, Wl, C, M, K, N);
}

// ---------------- per-graph LayerNorm + ELU (embed stage) ----------------------------
__global__ void ln_graph_elu_kernel(const float* __restrict__ in, float* __restrict__ out,
                                    const float* __restrict__ w, const float* __restrict__ b) {
  const int g = blockIdx.x, t = threadIdx.x;  // 256 threads
  const float* xg = in + (size_t)g * NPG * HID;
  float* og = out + (size_t)g * NPG * HID;
  float vals[16];
  float s = 0.f, ss = 0.f;
#pragma unroll
  for (int i = 0; i < 16; i++) {
    float v = xg[t + i * 256];
    vals[i] = v; s += v; ss += v * v;
  }
  __shared__ float ws0[4], ws1[4];
  for (int off = 32; off > 0; off >>= 1) { s += __shfl_down(s, off); ss += __shfl_down(ss, off); }
  int wid = t >> 6, lane = t & 63;
  if (lane == 0) { ws0[wid] = s; ws1[wid] = ss; }
  __syncthreads();
  if (t == 0) {
    float S = 0.f, SS = 0.f;
    for (int i = 0; i < 4; i++) { S += ws0[i]; SS += ws1[i]; }
    float mean = S / 4096.f;
    float var = SS / 4096.f - mean * mean;
    ws0[0] = mean; ws1[0] = rsqrtf(var + 1e-5f);
  }
  __syncthreads();
  float mean = ws0[0], inv = ws1[0];
#pragma unroll
  for (int i = 0; i < 16; i++) {
    int idx = t + i * 256;
    int ch = idx & 127;
    float y = (vals[i] - mean) * inv * w[ch] + b[ch];
    og[idx] = y > 0.f ? y : expm1f(y);
  }
}

// ==================== MEGA: full tconv step (+optional SAGPool) =====================
// r18 structure (batched drugs) + ILP surgery: dual-accumulator MF3D and full
// unrolls to shorten dependent MFMA chains (r12 showed barriers aren't binding;
// intra-phase chain latency is). VGPR headroom 64->128 is free (LDS-bound occ).
template<bool POOL>
__global__ __launch_bounds__(256, 4) void mega_kernel(
    float* __restrict__ xbA, float* __restrict__ eaA,
    float* __restrict__ xbB, float* __restrict__ eaB,
    const ushortb* __restrict__ Wqkvh, const ushortb* __restrict__ Wqkvl,  // [384][128]
    const ushortb* __restrict__ Wsh, const ushortb* __restrict__ Wsl,      // [128][128]
    const ushortb* __restrict__ WeTh, const ushortb* __restrict__ WeTl,    // [128][64]
    const ushortb* __restrict__ Wuph, const ushortb* __restrict__ Wupl,    // [64][64]
    const float* __restrict__ bqkv_, const float* __restrict__ bs_,
    const float* __restrict__ bup_, const float* __restrict__ lnw_,
    const float* __restrict__ lnb_,
    const float* __restrict__ w_rel, const float* __restrict__ b_rel,
    const float* __restrict__ w_root, const float* __restrict__ W_re,
    const float* __restrict__ b_re, float* __restrict__ outpA,
    float* __restrict__ outpB, int blk,
    const int* __restrict__ srcA, const int* __restrict__ dstA,
    const int* __restrict__ srcB, const int* __restrict__ dstB) {
  int g = blockIdx.x;
  float* xb = xbA; float* ea = eaA; float* outp = outpA;
  const int* src = srcA; const int* dst = dstA;
  if (g >= NGRAPH) {
    g -= NGRAPH;
    xb = xbB; ea = eaB; outp = outpB; src = srcB; dst = dstB;
  }
  const int t = threadIdx.x;  // 256 threads = 4 waves
  const int lane = t & 63, w = t >> 6, l16 = lane & 15, lk = lane >> 4;
  __shared__ float el[EPG * ES];        // e-tile / [32][XS] skip+xnew / gl @4224
  __shared__ float qs2[NPG * ES];       // q per head; later easum partials
  __shared__ float ks2[NPG * ES];       // k then v per head
  __shared__ unsigned char lists[NPG * EPG];
  __shared__ int deg_[NPG];
  __shared__ int sl[EPG], dl[EPG];
  __shared__ float alE[128];            // raw logits per head / pool score+easum
  __shared__ float red0[NPG], red1[NPG];

  if (t < EPG) { sl[t] = src[g * EPG + t] - g * NPG; dl[t] = dst[g * EPG + t] - g * NPG; }
  if (t < NPG) {  // CSR build, deterministic edge order
    int c = 0;
    for (int e = 0; e < EPG; e++)
      if (dl[e] == t) lists[t * EPG + (c++)] = (unsigned char)e;
    deg_[t] = c;
  }

  // persistent x fragments (rows m*16+l16, k-chunks kc*32+lk*8)
  bf16x8_t xh[2][4], xL[2][4];
#pragma unroll
  for (int m = 0; m < 2; m++)
#pragma unroll
    for (int kc = 0; kc < 4; kc++)
      split8(xb + ((size_t)g * NPG + m * 16 + l16) * HID + kc * 32 + lk * 8,
             xh[m][kc], xL[m][kc]);
  const float* eag = ea + ((size_t)g * EPG + w * 16 + l16) * 64;

  float accH0[8], accH1[8];
#pragma unroll
  for (int c = 0; c < 8; c++) { accH0[c] = 0.f; accH1[c] = 0.f; }

  // q/k projection helper: 32x64 output, dual-acc per output row-half
  auto proj = [&](int baseN, float* dstL) {
    f32x4 a0A = (f32x4)0.f, a0B = (f32x4)0.f;
    f32x4 a1A = (f32x4)0.f, a1B = (f32x4)0.f;
#pragma unroll
    for (int kc = 0; kc < 4; kc++) {
      size_t o = (size_t)(baseN + w * 16 + l16) * HID + kc * 32 + lk * 8;
      bf16x8_t bh = *(const bf16x8_t*)(Wqkvh + o);
      bf16x8_t bl = *(const bf16x8_t*)(Wqkvl + o);
      MF3D(a0A, a0B, xh[0][kc], xL[0][kc], bh, bl);
      MF3D(a1A, a1B, xh[1][kc], xL[1][kc], bh, bl);
    }
    f32x4 pa0 = a0A + a0B, pa1 = a1A + a1B;
    float bv = bqkv_[baseN + w * 16 + l16];
#pragma unroll
    for (int r = 0; r < 4; r++) {
      dstL[(lk * 4 + r) * ES + w * 16 + l16] = pa0[r] + bv;
      dstL[(16 + lk * 4 + r) * ES + w * 16 + l16] = pa1[r] + bv;
    }
  };

  auto head = [&](const int h, float (&acc8)[8]) {
    // ---- P0: e-GEMM + q/k projections ----
    {
      bf16x8_t ea0h, ea0l, ea1h, ea1l;
      split8(eag + lk * 8, ea0h, ea0l);
      split8(eag + 32 + lk * 8, ea1h, ea1l);
#pragma unroll
      for (int n = 0; n < 4; n++) {
        f32x4 aA = (f32x4)0.f, aB = (f32x4)0.f;
        size_t o0 = (size_t)(h * 64 + n * 16 + l16) * 64 + lk * 8;
        bf16x8_t bh0 = *(const bf16x8_t*)(WeTh + o0);
        bf16x8_t bl0 = *(const bf16x8_t*)(WeTl + o0);
        MF3D(aA, aB, ea0h, ea0l, bh0, bl0);
        bf16x8_t bh1 = *(const bf16x8_t*)(WeTh + o0 + 32);
        bf16x8_t bl1 = *(const bf16x8_t*)(WeTl + o0 + 32);
        MF3D(aA, aB, ea1h, ea1l, bh1, bl1);
        f32x4 acc = aA + aB;
#pragma unroll
        for (int r = 0; r < 4; r++)
          el[(w * 16 + lk * 4 + r) * ES + n * 16 + l16] = acc[r];
      }
    }
    proj(h * 64, qs2);          // q
    proj(128 + h * 64, ks2);    // k
    __syncthreads();            // A
    // ---- P1: logits (raw, no max needed) ----
    {
      const int e2 = t >> 2, part = t & 3;
      const float* qp = qs2 + dl[e2] * ES + part * 16;
      const float* kp = ks2 + sl[e2] * ES + part * 16;
      const float* ep = el + e2 * ES + part * 16;
      float s = 0.f;
#pragma unroll
      for (int c = 0; c < 16; c += 4) {
        float4 qv = *(const float4*)(qp + c);
        float4 kv = *(const float4*)(kp + c);
        float4 ev = *(const float4*)(ep + c);
        s += qv.x * (kv.x + ev.x) + qv.y * (kv.y + ev.y) +
             qv.z * (kv.z + ev.z) + qv.w * (kv.w + ev.w);
      }
      s += __shfl_xor(s, 1);
      s += __shfl_xor(s, 2);
      if (part == 0) alE[e2] = s * 0.125f;
    }
    __syncthreads();            // B (k-reads complete; logits final)
    // ---- P2: v-GEMM (overwrites k slot) + per-node sum(exp) ----
    f32x4 v0A = (f32x4)0.f, v0B = (f32x4)0.f;
    f32x4 v1A = (f32x4)0.f, v1B = (f32x4)0.f;
#pragma unroll
    for (int kc = 0; kc < 4; kc++) {
      size_t o = (size_t)(256 + h * 64 + w * 16 + l16) * HID + kc * 32 + lk * 8;
      bf16x8_t bh = *(const bf16x8_t*)(Wqkvh + o);
      bf16x8_t bl = *(const bf16x8_t*)(Wqkvl + o);
      MF3D(v0A, v0B, xh[0][kc], xL[0][kc], bh, bl);
      MF3D(v1A, v1B, xh[1][kc], xL[1][kc], bh, bl);
    }
    {
      const int n = t >> 3, part = t & 7;
      float su = 0.f;
#pragma unroll 1
      for (int i = 0; i < 8; i++) {
        int e2 = part * 8 + i;
        if (dl[e2] == n) su += expf(alE[e2]);
      }
      su += __shfl_xor(su, 1);
      su += __shfl_xor(su, 2);
      su += __shfl_xor(su, 4);
      if (part == 0) red1[n] = su;
    }
    {
      f32x4 va0 = v0A + v0B, va1 = v1A + v1B;
      float bv = bqkv_[256 + h * 64 + w * 16 + l16];
#pragma unroll
      for (int r = 0; r < 4; r++) {
        ks2[(lk * 4 + r) * ES + w * 16 + l16] = va0[r] + bv;
        ks2[(16 + lk * 4 + r) * ES + w * 16 + l16] = va1[r] + bv;
      }
    }
    __syncthreads();            // C
    // ---- P3: scatter via CSR, alpha inline ----
    {
      const int n = t >> 3, cg = t & 7;
      const float inv = 1.f / (red1[n] + 1e-16f);
      const int dg = deg_[n];
      for (int i = 0; i < dg; i++) {
        const int e2 = lists[n * EPG + i];
        const float a = expf(alE[e2]) * inv;
        const float* vp = ks2 + sl[e2] * ES + cg * 8;
        const float* ep = el + e2 * ES + cg * 8;
        float4 v0 = *(const float4*)vp, v1 = *(const float4*)(vp + 4);
        float4 e0 = *(const float4*)ep, e1 = *(const float4*)(ep + 4);
        acc8[0] += a * (v0.x + e0.x); acc8[1] += a * (v0.y + e0.y);
        acc8[2] += a * (v0.z + e0.z); acc8[3] += a * (v0.w + e0.w);
        acc8[4] += a * (v1.x + e1.x); acc8[5] += a * (v1.y + e1.y);
        acc8[6] += a * (v1.z + e1.z); acc8[7] += a * (v1.w + e1.w);
      }
    }
    __syncthreads();            // D: el/qs2/ks2 free for next phase
  };

  head(0, accH0);
  head(1, accH1);

  // ---- skip GEMM -> el as [32][XS] (dual-acc) ----
  {
#pragma unroll
    for (int n = 0; n < 2; n++) {
      f32x4 s0A = (f32x4)0.f, s0B = (f32x4)0.f;
      f32x4 s1A = (f32x4)0.f, s1B = (f32x4)0.f;
#pragma unroll
      for (int kc = 0; kc < 4; kc++) {
        size_t o = (size_t)(w * 32 + n * 16 + l16) * HID + kc * 32 + lk * 8;
        bf16x8_t bh = *(const bf16x8_t*)(Wsh + o);
        bf16x8_t bl = *(const bf16x8_t*)(Wsl + o);
        MF3D(s0A, s0B, xh[0][kc], xL[0][kc], bh, bl);
        MF3D(s1A, s1B, xh[1][kc], xL[1][kc], bh, bl);
      }
      f32x4 sa0 = s0A + s0B, sa1 = s1A + s1B;
      int col = w * 32 + n * 16 + l16;
      float bv = bs_[col];
#pragma unroll
      for (int r = 0; r < 4; r++) {
        el[(lk * 4 + r) * XS + col] = sa0[r] + bv;
        el[(16 + lk * 4 + r) * XS + col] = sa1[r] + bv;
      }
    }
  }
  // ---- ea update: ELU(ea@Wup+bup) -> global (+ua kept for POOL easum) ----
  f32x4 ua[4];
  {
    bf16x8_t ea0h, ea0l, ea1h, ea1l;
    split8(eag + lk * 8, ea0h, ea0l);
    split8(eag + 32 + lk * 8, ea1h, ea1l);
#pragma unroll
    for (int n = 0; n < 4; n++) {
      f32x4 aA = (f32x4)0.f, aB = (f32x4)0.f;
      size_t o0 = (size_t)(n * 16 + l16) * 64 + lk * 8;
      bf16x8_t bh0 = *(const bf16x8_t*)(Wuph + o0);
      bf16x8_t bl0 = *(const bf16x8_t*)(Wupl + o0);
      MF3D(aA, aB, ea0h, ea0l, bh0, bl0);
      bf16x8_t bh1 = *(const bf16x8_t*)(Wuph + o0 + 32);
      bf16x8_t bl1 = *(const bf16x8_t*)(Wupl + o0 + 32);
      MF3D(aA, aB, ea1h, ea1l, bh1, bl1);
      f32x4 acc = aA + aB;
      int col = n * 16 + l16;
      float bv = bup_[col];
#pragma unroll
      for (int r = 0; r < 4; r++) {
        float y = acc[r] + bv;
        y = y > 0.f ? y : expm1f(y);
        ua[n][r] = y;
        ea[((size_t)g * EPG + w * 16 + lk * 4 + r) * 64 + col] = y;
      }
    }
  }
  __syncthreads();  // skip writes visible
  // ---- graph-LN + ELU: thread owns (n = t>>3, cols cg*8 per head) ----
  {
    const int n = t >> 3, cg = t & 7;
    float v16[16];
#pragma unroll
    for (int c = 0; c < 8; c++) {
      v16[c] = accH0[c] + el[n * XS + cg * 8 + c];
      v16[8 + c] = accH1[c] + el[n * XS + 64 + cg * 8 + c];
    }
    float s = 0.f, ss = 0.f;
#pragma unroll
    for (int j = 0; j < 16; j++) { s += v16[j]; ss += v16[j] * v16[j]; }
    for (int o2 = 32; o2 > 0; o2 >>= 1) { s += __shfl_down(s, o2); ss += __shfl_down(ss, o2); }
    if (lane == 0) { red0[w] = s; red1[w] = ss; }
    __syncthreads();
    if (t == 0) {
      float S = red0[0] + red0[1] + red0[2] + red0[3];
      float SS = red1[0] + red1[1] + red1[2] + red1[3];
      float mean = S / 4096.f;
      float var = SS / 4096.f - mean * mean;
      red0[0] = mean; red1[0] = rsqrtf(var + 1e-5f);
    }
    __syncthreads();
    float mean = red0[0], inv = red1[0];
    float* xg = xb + (size_t)g * NPG * HID;
#pragma unroll
    for (int hh = 0; hh < 2; hh++)
#pragma unroll
      for (int c = 0; c < 8; c++) {
        int col = hh * 64 + cg * 8 + c;
        float y = (v16[hh * 8 + c] - mean) * inv * lnw_[col] + lnb_[col];
        y = y > 0.f ? y : expm1f(y);
        xg[n * HID + col] = y;
        el[n * XS + col] = y;  // xnew for POOL
      }
  }

  if constexpr (POOL) {
    __syncthreads();  // xnew visible
    // P1: easum wave-partials + score
    {
#pragma unroll
      for (int n = 0; n < 4; n++) {
        float s = ua[n][0] + ua[n][1] + ua[n][2] + ua[n][3];
        s += __shfl_xor(s, 16);
        s += __shfl_xor(s, 32);
        if (lk == 0) qs2[w * 64 + n * 16 + l16] = s;
      }
      // score[n] = b_rel + agg[n]·w_rel + x[n]·w_root  (8 lanes/node, 16 cols each)
      const int n = t >> 3, part = t & 7;
      float s = 0.f;
      for (int c = part * 16; c < part * 16 + 16; c++)
        s += el[n * XS + c] * w_root[c];
      const int dg = deg_[n];
      for (int i = 0; i < dg; i++) {
        int sn = sl[lists[n * EPG + i]];
        for (int c = part * 16; c < part * 16 + 16; c++)
          s += el[sn * XS + c] * w_rel[c];
      }
      s += __shfl_xor(s, 1);
      s += __shfl_xor(s, 2);
      s += __shfl_xor(s, 4);
      if (part == 0) alE[n] = s + b_rel[0];
    }
    __syncthreads();
    // P2: easum combine (t<64) + score softmax (wave 2 lanes 0..31)
    if (t < 64)
      alE[64 + t] = qs2[t] + qs2[64 + t] + qs2[128 + t] + qs2[192 + t];
    if (t >= 128 && t < 160) {
      int n = t - 128;
      float sc = alE[n];
      float m = sc;
      for (int o2 = 1; o2 <= 16; o2 <<= 1) m = fmaxf(m, __shfl_xor(m, o2));
      float e = expf(sc - m);
      float su = e;
      for (int o2 = 1; o2 <= 16; o2 <<= 1) su += __shfl_xor(su, o2);
      alE[n] = e / (su + 1e-16f);
    }
    __syncthreads();
    // P3: g[ch] = sum_n score[n]*x[n][ch]; ge = ELU(easum@W_re+b_re); norm
    if (t < HID) {
      const int ch = t;
      float gv = 0.f;
      for (int n = 0; n < NPG; n++) gv += alE[n] * el[n * XS + ch];
      float s2 = b_re[ch];
      for (int k2 = 0; k2 < 64; k2++) s2 += alE[64 + k2] * W_re[k2 * HID + ch];
      s2 = s2 > 0.f ? s2 : expm1f(s2);
      float gl = gv * s2;
      el[4224 + ch] = gl;
      float sq = gl * gl;
      for (int o2 = 32; o2 > 0; o2 >>= 1) sq += __shfl_down(sq, o2);
      if (lane == 0) red0[w] = sq;
    }
    __syncthreads();
    if (t == 0) red1[0] = fmaxf(sqrtf(red0[0] + red0[1]), 1e-12f);
    __syncthreads();
    if (t < HID)
      outp[((size_t)g * NBLK + blk) * HID + t] = el[4224 + t] / red1[0];
  }
}

// ---------------- row LayerNorm over 128 channels ------------------------------------
__global__ void ln_row_kernel(const float* __restrict__ in, float* __restrict__ out,
                              const float* __restrict__ w, const float* __restrict__ b) {
  const int r = blockIdx.x, t = threadIdx.x;  // 128 threads
  float v = in[(size_t)r * HID + t];
  float s = v, ss = v * v;
  for (int off = 32; off > 0; off >>= 1) { s += __shfl_down(s, off); ss += __shfl_down(ss, off); }
  __shared__ float s0[2], s1[2];
  if ((t & 63) == 0) { s0[t >> 6] = s; s1[t >> 6] = ss; }
  __syncthreads();
  float S = s0[0] + s0[1], SS = s1[0] + s1[1];
  float mean = S / 128.f, var = SS / 128.f - mean * mean;
  out[(size_t)r * HID + t] = (v - mean) * rsqrtf(var + 1e-5f) * w[t] + b[t];
}

// ---------------- co-attention core: per (batch, head), seq-len 4 --------------------
__global__ void coattn_kernel(const float* __restrict__ qb, const float* __restrict__ kvb,
                              float* __restrict__ ob) {
  const int bh = blockIdx.x, b = bh >> 3, h = bh & 7, t = threadIdx.x;  // 64 threads
  __shared__ float attn[4][4];
  __shared__ float red[64];
  const int pair = t >> 2, part = t & 3;
  const int n = pair >> 2, m = pair & 3;
  const float* qp = qb + ((size_t)(b * 4 + n) * (CAH * CAD)) + h * CAD;
  const float* kp = kvb + ((size_t)(b * 4 + m) * (2 * CAH * CAD)) + h * CAD;
  float s = 0.f;
  for (int d = part * 32; d < part * 32 + 32; d++) s += qp[d] * kp[d];
  red[t] = s;
  __syncthreads();
  if (t < 16) {
    float sc = (red[t * 4] + red[t * 4 + 1] + red[t * 4 + 2] + red[t * 4 + 3]) * 0.08838834764831845f;
    attn[t >> 2][t & 3] = sc;
  }
  __syncthreads();
  if (t < 4) {
    float m_ = -1e30f;
    for (int j = 0; j < 4; j++) m_ = fmaxf(m_, attn[t][j]);
    float ex[4], su = 0.f;
    for (int j = 0; j < 4; j++) { ex[j] = expf(attn[t][j] - m_); su += ex[j]; }
    for (int j = 0; j < 4; j++) attn[t][j] = ex[j] / su;
  }
  __syncthreads();
  for (int i = t; i < 512; i += 64) {
    int n2 = i >> 7, d = i & 127;
    float acc = 0.f;
    for (int m2 = 0; m2 < 4; m2++)
      acc += attn[n2][m2] * kvb[((size_t)(b * 4 + m2) * (2 * CAH * CAD)) + CAH * CAD + h * CAD + d];
    ob[((size_t)(b * 4 + n2) * (CAH * CAD)) + h * CAD + d] = acc;
  }
}

// ---------------- final: m = ha . ta^T -> merge -> softmax ---------------------------
__global__ void final_kernel(const float* __restrict__ ha, const float* __restrict__ ta,
                             const float* __restrict__ Wm, const float* __restrict__ bm,
                             float* __restrict__ out) {
  const int b = blockIdx.x, t = threadIdx.x;  // 64 threads
  __shared__ float mm[16];
  if (t < 16) {
    int n = t >> 2, m2 = t & 3;
    const float* hp = ha + (size_t)(b * 4 + n) * HID;
    const float* tp = ta + (size_t)(b * 4 + m2) * HID;
    float s = 0.f;
    for (int c = 0; c < HID; c++) s += hp[c] * tp[c];
    mm[t] = s;
  }
  __syncthreads();
  if (t == 0) {
    float l0 = bm[0], l1 = bm[1];
    for (int j = 0; j < 16; j++) { l0 += mm[j] * Wm[j * 2]; l1 += mm[j] * Wm[j * 2 + 1]; }
    float m_ = fmaxf(l0, l1);
    float e0 = expf(l0 - m_), e1 = expf(l1 - m_);
    float su = e0 + e1;
    out[b * 2] = e0 / su;
    out[b * 2 + 1] = e1 / su;
  }
}

// ====================================================================================
extern "C" void kernel_launch(void* const* d_in, const int* in_sizes, int n_in,
                              void* d_out, int out_size, void* d_ws, size_t ws_size,
                              hipStream_t stream) {
  const float* xin[2]  = {(const float*)d_in[0], (const float*)d_in[1]};
  const float* eain[2] = {(const float*)d_in[2], (const float*)d_in[3]};
  const float* W_node = (const float*)d_in[4];
  const float* b_node = (const float*)d_in[5];
  const float* W_edge = (const float*)d_in[6];
  const float* b_edge = (const float*)d_in[7];
  const float* ln0_w = (const float*)d_in[8];
  const float* ln0_b = (const float*)d_in[9];
  const float* Wq = (const float*)d_in[10];
  const float* bq = (const float*)d_in[11];
  const float* Wk = (const float*)d_in[12];
  const float* bk = (const float*)d_in[13];
  const float* Wv = (const float*)d_in[14];
  const float* bv = (const float*)d_in[15];
  const float* We = (const float*)d_in[16];
  const float* Wskip = (const float*)d_in[17];
  const float* bs = (const float*)d_in[18];
  const float* Wup = (const float*)d_in[19];
  const float* bup = (const float*)d_in[20];
  const float* lnw = (const float*)d_in[21];
  const float* lnb = (const float*)d_in[22];
  const float* w_rel = (const float*)d_in[23];
  const float* b_rel = (const float*)d_in[24];
  const float* w_root = (const float*)d_in[25];
  const float* W_re = (const float*)d_in[26];
  const float* b_re = (const float*)d_in[27];
  const float* ca_lw = (const float*)d_in[28];
  const float* ca_lb = (const float*)d_in[29];
  const float* Wq_ca = (const float*)d_in[30];
  const float* Wkv_ca = (const float*)d_in[31];
  const float* Wo_ca = (const float*)d_in[32];
  const float* W_merge = (const float*)d_in[33];
  const float* b_merge = (const float*)d_in[34];
  const int* ei[2] = {(const int*)d_in[35], (const int*)d_in[36]};
  float* out = (float*)d_out;
  (void)in_sizes; (void)n_in; (void)out_size;

  char* base = (char*)d_ws;
  size_t off = 0;
  auto alloc = [&](size_t elems) {
    float* r = (float*)(base + off);
    off += ((elems * 4 + 255) & ~(size_t)255);
    return r;
  };
  auto allocb = [&](size_t elems) {  // bf16 elems
    ushortb* r = (ushortb*)(base + off);
    off += ((elems * 2 + 255) & ~(size_t)255);
    return r;
  };
  float* xb  = alloc((size_t)NNODE * HID);      // 32 MiB (also co-attn q buffer)
  float* ea  = alloc((size_t)NEDGE * 64);       // 32 MiB (also co-attn o buffer)
  float* big = alloc((size_t)8192 * 2048);      // 64 MiB (drug-2 xb/ea; later co-attn kv)
  float* hs  = alloc((size_t)NGRAPH * NBLK * HID);
  float* ts  = alloc((size_t)NGRAPH * NBLK * HID);
  float* rhn = alloc((size_t)NGRAPH * NBLK * HID);
  float* rtn = alloc((size_t)NGRAPH * NBLK * HID);
  float* hab = alloc((size_t)NGRAPH * NBLK * HID);
  float* tab = alloc((size_t)NGRAPH * NBLK * HID);
  ushortb* Wqkvh = allocb((size_t)8 * 384 * 128); ushortb* Wqkvl = allocb((size_t)8 * 384 * 128);
  ushortb* Wsh = allocb(8 * 16384);  ushortb* Wsl = allocb(8 * 16384);
  ushortb* Wuph = allocb(8 * 4096);  ushortb* Wupl = allocb(8 * 4096);
  ushortb* WeTh = allocb(8 * 8192);  ushortb* WeTl = allocb(8 * 8192);
  ushortb* Wqcah = allocb(131072);   ushortb* Wqcal = allocb(131072);
  ushortb* Wkvh = allocb(262144);    ushortb* Wkvl = allocb(262144);
  ushortb* Woh = allocb(131072);     ushortb* Wol = allocb(131072);
  float* bqkv = alloc(8 * 384);
  if (off > ws_size) return;  // diagnostic: fail with absmax, never fault

  float* xb2 = big;                          // drug-2 node state (32 MiB)
  float* ea2 = big + (size_t)NNODE * HID;    // drug-2 edge state (32 MiB)
  float* qc  = xb;   // co-attn aliases (xb/ea/big dead after main loop)
  float* kvc = big;
  float* oc  = ea;

  auto convw = [&](const float* s, ushortb* h, ushortb* l, int K, int N, int B,
                   int dstN, int nOff) {
    int tot = B * K * N;
    convw_kernel<<<(tot + 255) / 256, 256, 0, stream>>>(s, h, l, K, N, tot, dstN, nOff);
  };
  convw(Wq, Wqkvh, Wqkvl, 128, 128, 8, 384, 0);
  convw(Wk, Wqkvh, Wqkvl, 128, 128, 8, 384, 128);
  convw(Wv, Wqkvh, Wqkvl, 128, 128, 8, 384, 256);
  convw(Wskip, Wsh, Wsl, 128, 128, 8, 128, 0);
  convw(Wup, Wuph, Wupl, 64, 64, 8, 64, 0);
  convw(We, WeTh, WeTl, 64, 128, 8, 128, 0);
  convw(Wq_ca, Wqcah, Wqcal, 128, 1024, 1, 1024, 0);
  convw(Wkv_ca, Wkvh, Wkvl, 128, 2048, 1, 2048, 0);
  convw(Wo_ca, Woh, Wol, 1024, 128, 1, 128, 0);
  bcat_kernel<<<(8 * 384 + 255) / 256, 256, 0, stream>>>(bq, bk, bv, bqkv);

  // embeds for BOTH drugs
  run_gemm(xin[0], W_node, b_node, xb, NNODE, FINDIM, HID, false, stream);
  run_gemm(xin[1], W_node, b_node, xb2, NNODE, FINDIM, HID, false, stream);
  ln_graph_elu_kernel<<<NGRAPH, 256, 0, stream>>>(xb, xb, ln0_w, ln0_b);
  ln_graph_elu_kernel<<<NGRAPH, 256, 0, stream>>>(xb2, xb2, ln0_w, ln0_b);
  run_gemm(eain[0], W_edge, b_edge, ea, NEDGE, EINDIM, 64, true, stream);
  run_gemm(eain[1], W_edge, b_edge, ea2, NEDGE, EINDIM, 64, true, stream);

  // 8 batched mega launches (both drugs per launch)
  for (int i = 0; i < NBLK; ++i) {
    int pi0 = i * 2, pi1 = i * 2 + 1;
    mega_kernel<false><<<2 * NGRAPH, 256, 0, stream>>>(
        xb, ea, xb2, ea2,
        Wqkvh + (size_t)pi0 * 49152, Wqkvl + (size_t)pi0 * 49152,
        Wsh + (size_t)pi0 * 16384, Wsl + (size_t)pi0 * 16384,
        WeTh + (size_t)pi0 * 8192, WeTl + (size_t)pi0 * 8192,
        Wuph + (size_t)pi0 * 4096, Wupl + (size_t)pi0 * 4096,
        bqkv + pi0 * 384, bs + pi0 * 128, bup + pi0 * 64,
        lnw + pi0 * 128, lnb + pi0 * 128,
        w_rel, b_rel, w_root, W_re, b_re, nullptr, nullptr, 0,
        ei[0], ei[0] + NEDGE, ei[1], ei[1] + NEDGE);
    mega_kernel<true><<<2 * NGRAPH, 256, 0, stream>>>(
        xb, ea, xb2, ea2,
        Wqkvh + (size_t)pi1 * 49152, Wqkvl + (size_t)pi1 * 49152,
        Wsh + (size_t)pi1 * 16384, Wsl + (size_t)pi1 * 16384,
        WeTh + (size_t)pi1 * 8192, WeTl + (size_t)pi1 * 8192,
        Wuph + (size_t)pi1 * 4096, Wupl + (size_t)pi1 * 4096,
        bqkv + pi1 * 384, bs + pi1 * 128, bup + pi1 * 64,
        lnw + pi1 * 128, lnb + pi1 * 128,
        w_rel, b_rel, w_root, W_re, b_re, hs, ts, i,
        ei[0], ei[0] + NEDGE, ei[1], ei[1] + NEDGE);
  }

  ln_row_kernel<<<NGRAPH * NBLK, 128, 0, stream>>>(hs, rhn, ca_lw, ca_lb);
  ln_row_kernel<<<NGRAPH * NBLK, 128, 0, stream>>>(ts, rtn, ca_lw, ca_lb);
  // ha = coattn(q from rh, kv from rt)
  run_mf8(rhn, Wqcah, Wqcal, qc, NGRAPH * NBLK, 128, 1024, stream);
  run_mf8(rtn, Wkvh, Wkvl, kvc, NGRAPH * NBLK, 128, 2048, stream);
  coattn_kernel<<<NGRAPH * CAH, 64, 0, stream>>>(qc, kvc, oc);
  run_mf8(oc, Woh, Wol, hab, NGRAPH * NBLK, 1024, 128, stream);
  // ta = coattn(q from rt, kv from rh)
  run_mf8(rtn, Wqcah, Wqcal, qc, NGRAPH * NBLK, 128, 1024, stream);
  run_mf8(rhn, Wkvh, Wkvl, kvc, NGRAPH * NBLK, 128, 2048, stream);
  coattn_kernel<<<NGRAPH * CAH, 64, 0, stream>>>(qc, kvc, oc);
  run_mf8(oc, Woh, Wol, tab, NGRAPH * NBLK, 1024, 128, stream);

  final_kernel<<<NGRAPH, 64, 0, stream>>>(hab, tab, W_merge, b_merge, out);
}

// Round 20
// 3206.097 us; speedup vs baseline: 1.0635x; 1.0635x over previous
//
#include <hip/hip_runtime.h>
#include <cstddef>
#include <cstdint>

#define NGRAPH 2048
#define NPG    32
#define EPG    64
#define NNODE  (NGRAPH*NPG)   // 65536
#define NEDGE  (NGRAPH*EPG)   // 131072
#define FINDIM 70
#define EINDIM 6
#define HID    128
#define NBLK   4
#define CAH    8
#define CAD    128
#define ES     68             // per-head e/k/q LDS stride (f32)
#define XS     132            // xnew/skip LDS stride inside el region

typedef __attribute__((ext_vector_type(8))) short bf16x8_t;
typedef __attribute__((ext_vector_type(4))) float f32x4;
typedef unsigned short ushortb;

#define MF3(accv, Ah_, Al_, Bh_, Bl_)                                          \
  accv = __builtin_amdgcn_mfma_f32_16x16x32_bf16(Ah_, Bh_, accv, 0, 0, 0);     \
  accv = __builtin_amdgcn_mfma_f32_16x16x32_bf16(Ah_, Bl_, accv, 0, 0, 0);     \
  accv = __builtin_amdgcn_mfma_f32_16x16x32_bf16(Al_, Bh_, accv, 0, 0, 0);

__device__ inline void split8(const float* p, bf16x8_t& h, bf16x8_t& l) {
  float4 v0 = *(const float4*)p, v1 = *(const float4*)(p + 4);
  float vv[8] = {v0.x, v0.y, v0.z, v0.w, v1.x, v1.y, v1.z, v1.w};
#pragma unroll
  for (int j = 0; j < 8; j++) {
    unsigned u = __builtin_bit_cast(unsigned, vv[j]);
    h[j] = (short)(u >> 16);
    float r = vv[j] - __builtin_bit_cast(float, u & 0xFFFF0000u);
    l[j] = (short)(__builtin_bit_cast(unsigned, r) >> 16);
  }
}

// ---------------- generic tiled f32 GEMM (K=70 / K=6 embeds) -------------------------
template<bool BIAS, bool ELU>
__global__ __launch_bounds__(256) void gemm_kernel(
    const float* __restrict__ A, const float* __restrict__ W,
    const float* __restrict__ bias, float* __restrict__ C,
    int M, int K, int Nc) {
  __shared__ float As[8][64];
  __shared__ float Bs[8][65];
  const int bm = blockIdx.y * 64, bn = blockIdx.x * 64;
  const int tid = threadIdx.x;
  const int tr = tid >> 4, tc = tid & 15;
  float acc[4][4];
#pragma unroll
  for (int i = 0; i < 4; i++)
#pragma unroll
    for (int j = 0; j < 4; j++) acc[i][j] = 0.f;
  for (int k0 = 0; k0 < K; k0 += 8) {
#pragma unroll
    for (int l = 0; l < 2; l++) {
      int idx = tid + l * 256;
      int r = idx >> 3, c = idx & 7;
      As[c][r] = (k0 + c < K) ? A[(size_t)(bm + r) * K + k0 + c] : 0.f;
      int rw = idx >> 6, cw = idx & 63;
      Bs[rw][cw] = (k0 + rw < K) ? W[(size_t)(k0 + rw) * Nc + bn + cw] : 0.f;
    }
    __syncthreads();
#pragma unroll
    for (int kk = 0; kk < 8; kk++) {
      float a_[4], w_[4];
#pragma unroll
      for (int i = 0; i < 4; i++) a_[i] = As[kk][tr * 4 + i];
#pragma unroll
      for (int j = 0; j < 4; j++) w_[j] = Bs[kk][tc * 4 + j];
#pragma unroll
      for (int i = 0; i < 4; i++)
#pragma unroll
        for (int j = 0; j < 4; j++) acc[i][j] += a_[i] * w_[j];
    }
    __syncthreads();
  }
#pragma unroll
  for (int i = 0; i < 4; i++) {
    int r = bm + tr * 4 + i;
#pragma unroll
    for (int j = 0; j < 4; j++) {
      int c = bn + tc * 4 + j;
      float v = acc[i][j];
      if (BIAS) v += bias[c];
      if (ELU) v = v > 0.f ? v : expm1f(v);
      C[(size_t)r * Nc + c] = v;
    }
  }
}

static void run_gemm(const float* A, const float* W, const float* bias, float* C,
                     int M, int K, int Nc, bool eluf, hipStream_t st) {
  dim3 grid(Nc / 64, M / 64), block(256);
  if (eluf) gemm_kernel<true, true><<<grid, block, 0, st>>>(A, W, bias, C, M, K, Nc);
  else      gemm_kernel<true, false><<<grid, block, 0, st>>>(A, W, bias, C, M, K, Nc);
}

// ------- weight f32[B][K][N] -> transposed bf16 hi/lo, dest [b][dstN][K] @ nOff ------
__global__ void convw_kernel(const float* __restrict__ src, ushortb* __restrict__ h,
                             ushortb* __restrict__ l, int K, int N, int total,
                             int dstN, int nOff) {
  int idx = blockIdx.x * 256 + threadIdx.x;
  if (idx >= total) return;
  int k = idx % K;
  int t2 = idx / K;
  int n = t2 % N;
  int b = t2 / N;
  float v = src[((size_t)b * K + k) * N + n];
  unsigned uv = __builtin_bit_cast(unsigned, v);
  ushortb hb = (ushortb)(uv >> 16);
  float hf = __builtin_bit_cast(float, uv & 0xFFFF0000u);
  float rr = v - hf;
  ushortb lb = (ushortb)(__builtin_bit_cast(unsigned, rr) >> 16);
  size_t didx = ((size_t)b * dstN + nOff + n) * K + k;
  h[didx] = hb;
  l[didx] = lb;
}

// ---------------- concat q/k/v biases -> [8][384] ------------------------------------
__global__ void bcat_kernel(const float* __restrict__ bq, const float* __restrict__ bk,
                            const float* __restrict__ bv, float* __restrict__ o) {
  int t = blockIdx.x * 256 + threadIdx.x;
  if (t >= 8 * 384) return;
  int pi = t / 384, c = t % 384, sel = c >> 7, cc = c & 127;
  const float* s = sel == 0 ? bq : (sel == 1 ? bk : bv);
  o[t] = s[pi * 128 + cc];
}

// ---------------- 8-wave MFMA GEMM (BM=128, BN=128) — co-attention projections -------
__global__ __launch_bounds__(512) void gemm_mfma8_kernel(
    const float* __restrict__ A, const ushortb* __restrict__ Wh,
    const ushortb* __restrict__ Wl, float* __restrict__ C, int M, int K, int N) {
  __shared__ ushortb Ah[128 * 40];
  __shared__ ushortb Al[128 * 40];
  const int bm = blockIdx.y * 128, bn = blockIdx.x * 128;
  const int tid = threadIdx.x, lane = tid & 63, w = tid >> 6;
  const int wr = w >> 1, wc = w & 1;
  const int l16 = lane & 15, lk = lane >> 4;
  f32x4 acc[2][4];
#pragma unroll
  for (int m = 0; m < 2; m++)
#pragma unroll
    for (int n = 0; n < 4; n++) acc[m][n] = (f32x4)0.f;

  for (int k0 = 0; k0 < K; k0 += 32) {
    __syncthreads();
#pragma unroll
    for (int p = 0; p < 2; p++) {
      int base = p * 2048 + tid * 4;
      int r = base >> 5, c = base & 31;
      const float4 v = *(const float4*)(A + (size_t)(bm + r) * K + k0 + c);
      unsigned u0 = __builtin_bit_cast(unsigned, v.x);
      unsigned u1 = __builtin_bit_cast(unsigned, v.y);
      unsigned u2 = __builtin_bit_cast(unsigned, v.z);
      unsigned u3 = __builtin_bit_cast(unsigned, v.w);
      ushort4 hv;
      hv.x = (ushortb)(u0 >> 16); hv.y = (ushortb)(u1 >> 16);
      hv.z = (ushortb)(u2 >> 16); hv.w = (ushortb)(u3 >> 16);
      float r0 = v.x - __builtin_bit_cast(float, u0 & 0xFFFF0000u);
      float r1 = v.y - __builtin_bit_cast(float, u1 & 0xFFFF0000u);
      float r2 = v.z - __builtin_bit_cast(float, u2 & 0xFFFF0000u);
      float r3 = v.w - __builtin_bit_cast(float, u3 & 0xFFFF0000u);
      ushort4 lv;
      lv.x = (ushortb)(__builtin_bit_cast(unsigned, r0) >> 16);
      lv.y = (ushortb)(__builtin_bit_cast(unsigned, r1) >> 16);
      lv.z = (ushortb)(__builtin_bit_cast(unsigned, r2) >> 16);
      lv.w = (ushortb)(__builtin_bit_cast(unsigned, r3) >> 16);
      *(ushort4*)(&Ah[r * 40 + c]) = hv;
      *(ushort4*)(&Al[r * 40 + c]) = lv;
    }
    __syncthreads();
    bf16x8_t bh[4], bl[4];
#pragma unroll
    for (int n = 0; n < 4; n++) {
      size_t o = (size_t)(bn + wc * 64 + n * 16 + l16) * K + k0 + lk * 8;
      bh[n] = *(const bf16x8_t*)(Wh + o);
      bl[n] = *(const bf16x8_t*)(Wl + o);
    }
    bf16x8_t ah[2], al2[2];
#pragma unroll
    for (int m = 0; m < 2; m++) {
      int ao = (wr * 32 + m * 16 + l16) * 40 + lk * 8;
      ah[m]  = *(const bf16x8_t*)(&Ah[ao]);
      al2[m] = *(const bf16x8_t*)(&Al[ao]);
    }
#pragma unroll
    for (int m = 0; m < 2; m++)
#pragma unroll
      for (int n = 0; n < 4; n++) {
        MF3(acc[m][n], ah[m], al2[m], bh[n], bl[n]);
      }
  }
#pragma unroll
  for (int m = 0; m < 2; m++)
#pragma unroll
    for (int n = 0; n < 4; n++) {
      int col = bn + wc * 64 + n * 16 + l16;
#pragma unroll
      for (int r = 0; r < 4; r++) {
        int row = bm + wr * 32 + m * 16 + lk * 4 + r;
        C[(size_t)row * N + col] = acc[m][n][r];
      }
    }
}

static void run_mf8(const float* A, const ushortb* Wh, const ushortb* Wl,
                    float* C, int M, int K, int N, hipStream_t st) {
  dim3 grid(N / 128, M / 128), block(512);
  gemm_mfma8_kernel<<<grid, block, 0, st>>>(A, Wh, Wl, C, M, K, N);
}

// ---------------- per-graph LayerNorm + ELU (embed stage) ----------------------------
__global__ void ln_graph_elu_kernel(const float* __restrict__ in, float* __restrict__ out,
                                    const float* __restrict__ w, const float* __restrict__ b) {
  const int g = blockIdx.x, t = threadIdx.x;  // 256 threads
  const float* xg = in + (size_t)g * NPG * HID;
  float* og = out + (size_t)g * NPG * HID;
  float vals[16];
  float s = 0.f, ss = 0.f;
#pragma unroll
  for (int i = 0; i < 16; i++) {
    float v = xg[t + i * 256];
    vals[i] = v; s += v; ss += v * v;
  }
  __shared__ float ws0[4], ws1[4];
  for (int off = 32; off > 0; off >>= 1) { s += __shfl_down(s, off); ss += __shfl_down(ss, off); }
  int wid = t >> 6, lane = t & 63;
  if (lane == 0) { ws0[wid] = s; ws1[wid] = ss; }
  __syncthreads();
  if (t == 0) {
    float S = 0.f, SS = 0.f;
    for (int i = 0; i < 4; i++) { S += ws0[i]; SS += ws1[i]; }
    float mean = S / 4096.f;
    float var = SS / 4096.f - mean * mean;
    ws0[0] = mean; ws1[0] = rsqrtf(var + 1e-5f);
  }
  __syncthreads();
  float mean = ws0[0], inv = ws1[0];
#pragma unroll
  for (int i = 0; i < 16; i++) {
    int idx = t + i * 256;
    int ch = idx & 127;
    float y = (vals[i] - mean) * inv * w[ch] + b[ch];
    og[idx] = y > 0.f ? y : expm1f(y);
  }
}

// ==================== MEGA: full tconv step (+optional SAGPool) =====================
// Final configuration (r18, best of 12 controlled experiments): r12 phase structure
// (raw-logit softmax, fused v-GEMM/sum, inline alpha scatter), batched over both
// drugs (grid = 2*NGRAPH). 4 blocks/CU, VGPR-64 remat equilibrium.
template<bool POOL>
__global__ __launch_bounds__(256, 4) void mega_kernel(
    float* __restrict__ xbA, float* __restrict__ eaA,
    float* __restrict__ xbB, float* __restrict__ eaB,
    const ushortb* __restrict__ Wqkvh, const ushortb* __restrict__ Wqkvl,  // [384][128]
    const ushortb* __restrict__ Wsh, const ushortb* __restrict__ Wsl,      // [128][128]
    const ushortb* __restrict__ WeTh, const ushortb* __restrict__ WeTl,    // [128][64]
    const ushortb* __restrict__ Wuph, const ushortb* __restrict__ Wupl,    // [64][64]
    const float* __restrict__ bqkv_, const float* __restrict__ bs_,
    const float* __restrict__ bup_, const float* __restrict__ lnw_,
    const float* __restrict__ lnb_,
    const float* __restrict__ w_rel, const float* __restrict__ b_rel,
    const float* __restrict__ w_root, const float* __restrict__ W_re,
    const float* __restrict__ b_re, float* __restrict__ outpA,
    float* __restrict__ outpB, int blk,
    const int* __restrict__ srcA, const int* __restrict__ dstA,
    const int* __restrict__ srcB, const int* __restrict__ dstB) {
  int g = blockIdx.x;
  float* xb = xbA; float* ea = eaA; float* outp = outpA;
  const int* src = srcA; const int* dst = dstA;
  if (g >= NGRAPH) {
    g -= NGRAPH;
    xb = xbB; ea = eaB; outp = outpB; src = srcB; dst = dstB;
  }
  const int t = threadIdx.x;  // 256 threads = 4 waves
  const int lane = t & 63, w = t >> 6, l16 = lane & 15, lk = lane >> 4;
  __shared__ float el[EPG * ES];        // e-tile / [32][XS] skip+xnew / gl @4224
  __shared__ float qs2[NPG * ES];       // q per head; later easum partials
  __shared__ float ks2[NPG * ES];       // k then v per head
  __shared__ unsigned char lists[NPG * EPG];
  __shared__ int deg_[NPG];
  __shared__ int sl[EPG], dl[EPG];
  __shared__ float alE[128];            // raw logits per head / pool score+easum
  __shared__ float red0[NPG], red1[NPG];

  if (t < EPG) { sl[t] = src[g * EPG + t] - g * NPG; dl[t] = dst[g * EPG + t] - g * NPG; }
  if (t < NPG) {  // CSR build, deterministic edge order
    int c = 0;
    for (int e = 0; e < EPG; e++)
      if (dl[e] == t) lists[t * EPG + (c++)] = (unsigned char)e;
    deg_[t] = c;
  }

  // persistent x fragments (rows m*16+l16, k-chunks kc*32+lk*8)
  bf16x8_t xh[2][4], xL[2][4];
#pragma unroll
  for (int m = 0; m < 2; m++)
#pragma unroll
    for (int kc = 0; kc < 4; kc++)
      split8(xb + ((size_t)g * NPG + m * 16 + l16) * HID + kc * 32 + lk * 8,
             xh[m][kc], xL[m][kc]);
  const float* eag = ea + ((size_t)g * EPG + w * 16 + l16) * 64;

  float accH0[8], accH1[8];
#pragma unroll
  for (int c = 0; c < 8; c++) { accH0[c] = 0.f; accH1[c] = 0.f; }

  // q/k projection helper: 32x64 output into dstL (cols w*16..w*16+15 per wave)
  auto proj = [&](int baseN, float* dstL) {
    f32x4 pa0 = (f32x4)0.f, pa1 = (f32x4)0.f;
#pragma unroll
    for (int kc = 0; kc < 4; kc++) {
      size_t o = (size_t)(baseN + w * 16 + l16) * HID + kc * 32 + lk * 8;
      bf16x8_t bh = *(const bf16x8_t*)(Wqkvh + o);
      bf16x8_t bl = *(const bf16x8_t*)(Wqkvl + o);
      MF3(pa0, xh[0][kc], xL[0][kc], bh, bl);
      MF3(pa1, xh[1][kc], xL[1][kc], bh, bl);
    }
    float bv = bqkv_[baseN + w * 16 + l16];
#pragma unroll
    for (int r = 0; r < 4; r++) {
      dstL[(lk * 4 + r) * ES + w * 16 + l16] = pa0[r] + bv;
      dstL[(16 + lk * 4 + r) * ES + w * 16 + l16] = pa1[r] + bv;
    }
  };

  auto head = [&](const int h, float (&acc8)[8]) {
    // ---- P0: e-GEMM + q/k projections ----
    {
      bf16x8_t ea0h, ea0l, ea1h, ea1l;
      split8(eag + lk * 8, ea0h, ea0l);
      split8(eag + 32 + lk * 8, ea1h, ea1l);
#pragma unroll 1
      for (int n = 0; n < 4; n++) {
        f32x4 acc = (f32x4)0.f;
        size_t o0 = (size_t)(h * 64 + n * 16 + l16) * 64 + lk * 8;
        bf16x8_t bh0 = *(const bf16x8_t*)(WeTh + o0);
        bf16x8_t bl0 = *(const bf16x8_t*)(WeTl + o0);
        MF3(acc, ea0h, ea0l, bh0, bl0);
        bf16x8_t bh1 = *(const bf16x8_t*)(WeTh + o0 + 32);
        bf16x8_t bl1 = *(const bf16x8_t*)(WeTl + o0 + 32);
        MF3(acc, ea1h, ea1l, bh1, bl1);
#pragma unroll
        for (int r = 0; r < 4; r++)
          el[(w * 16 + lk * 4 + r) * ES + n * 16 + l16] = acc[r];
      }
    }
    proj(h * 64, qs2);          // q
    proj(128 + h * 64, ks2);    // k
    __syncthreads();            // A
    // ---- P1: logits (raw, no max needed) ----
    {
      const int e2 = t >> 2, part = t & 3;
      const float* qp = qs2 + dl[e2] * ES + part * 16;
      const float* kp = ks2 + sl[e2] * ES + part * 16;
      const float* ep = el + e2 * ES + part * 16;
      float s = 0.f;
#pragma unroll
      for (int c = 0; c < 16; c += 4) {
        float4 qv = *(const float4*)(qp + c);
        float4 kv = *(const float4*)(kp + c);
        float4 ev = *(const float4*)(ep + c);
        s += qv.x * (kv.x + ev.x) + qv.y * (kv.y + ev.y) +
             qv.z * (kv.z + ev.z) + qv.w * (kv.w + ev.w);
      }
      s += __shfl_xor(s, 1);
      s += __shfl_xor(s, 2);
      if (part == 0) alE[e2] = s * 0.125f;
    }
    __syncthreads();            // B (k-reads complete; logits final)
    // ---- P2: v-GEMM (overwrites k slot) + per-node sum(exp) ----
    f32x4 va0 = (f32x4)0.f, va1 = (f32x4)0.f;
#pragma unroll
    for (int kc = 0; kc < 4; kc++) {
      size_t o = (size_t)(256 + h * 64 + w * 16 + l16) * HID + kc * 32 + lk * 8;
      bf16x8_t bh = *(const bf16x8_t*)(Wqkvh + o);
      bf16x8_t bl = *(const bf16x8_t*)(Wqkvl + o);
      MF3(va0, xh[0][kc], xL[0][kc], bh, bl);
      MF3(va1, xh[1][kc], xL[1][kc], bh, bl);
    }
    {
      const int n = t >> 3, part = t & 7;
      float su = 0.f;
#pragma unroll 1
      for (int i = 0; i < 8; i++) {
        int e2 = part * 8 + i;
        if (dl[e2] == n) su += expf(alE[e2]);
      }
      su += __shfl_xor(su, 1);
      su += __shfl_xor(su, 2);
      su += __shfl_xor(su, 4);
      if (part == 0) red1[n] = su;
    }
    {
      float bv = bqkv_[256 + h * 64 + w * 16 + l16];
#pragma unroll
      for (int r = 0; r < 4; r++) {
        ks2[(lk * 4 + r) * ES + w * 16 + l16] = va0[r] + bv;
        ks2[(16 + lk * 4 + r) * ES + w * 16 + l16] = va1[r] + bv;
      }
    }
    __syncthreads();            // C
    // ---- P3: scatter via CSR, alpha inline ----
    {
      const int n = t >> 3, cg = t & 7;
      const float inv = 1.f / (red1[n] + 1e-16f);
      const int dg = deg_[n];
      for (int i = 0; i < dg; i++) {
        const int e2 = lists[n * EPG + i];
        const float a = expf(alE[e2]) * inv;
        const float* vp = ks2 + sl[e2] * ES + cg * 8;
        const float* ep = el + e2 * ES + cg * 8;
        float4 v0 = *(const float4*)vp, v1 = *(const float4*)(vp + 4);
        float4 e0 = *(const float4*)ep, e1 = *(const float4*)(ep + 4);
        acc8[0] += a * (v0.x + e0.x); acc8[1] += a * (v0.y + e0.y);
        acc8[2] += a * (v0.z + e0.z); acc8[3] += a * (v0.w + e0.w);
        acc8[4] += a * (v1.x + e1.x); acc8[5] += a * (v1.y + e1.y);
        acc8[6] += a * (v1.z + e1.z); acc8[7] += a * (v1.w + e1.w);
      }
    }
    __syncthreads();            // D: el/qs2/ks2 free for next phase
  };

  head(0, accH0);
  head(1, accH1);

  // ---- skip GEMM -> el as [32][XS] ----
  {
#pragma unroll
    for (int n = 0; n < 2; n++) {
      f32x4 sa0 = (f32x4)0.f, sa1 = (f32x4)0.f;
#pragma unroll
      for (int kc = 0; kc < 4; kc++) {
        size_t o = (size_t)(w * 32 + n * 16 + l16) * HID + kc * 32 + lk * 8;
        bf16x8_t bh = *(const bf16x8_t*)(Wsh + o);
        bf16x8_t bl = *(const bf16x8_t*)(Wsl + o);
        MF3(sa0, xh[0][kc], xL[0][kc], bh, bl);
        MF3(sa1, xh[1][kc], xL[1][kc], bh, bl);
      }
      int col = w * 32 + n * 16 + l16;
      float bv = bs_[col];
#pragma unroll
      for (int r = 0; r < 4; r++) {
        el[(lk * 4 + r) * XS + col] = sa0[r] + bv;
        el[(16 + lk * 4 + r) * XS + col] = sa1[r] + bv;
      }
    }
  }
  // ---- ea update: ELU(ea@Wup+bup) -> global (+ua kept for POOL easum) ----
  f32x4 ua[4];
  {
    bf16x8_t ea0h, ea0l, ea1h, ea1l;
    split8(eag + lk * 8, ea0h, ea0l);
    split8(eag + 32 + lk * 8, ea1h, ea1l);
#pragma unroll
    for (int n = 0; n < 4; n++) {
      f32x4 acc = (f32x4)0.f;
      size_t o0 = (size_t)(n * 16 + l16) * 64 + lk * 8;
      bf16x8_t bh0 = *(const bf16x8_t*)(Wuph + o0);
      bf16x8_t bl0 = *(const bf16x8_t*)(Wupl + o0);
      MF3(acc, ea0h, ea0l, bh0, bl0);
      bf16x8_t bh1 = *(const bf16x8_t*)(Wuph + o0 + 32);
      bf16x8_t bl1 = *(const bf16x8_t*)(Wupl + o0 + 32);
      MF3(acc, ea1h, ea1l, bh1, bl1);
      int col = n * 16 + l16;
      float bv = bup_[col];
#pragma unroll
      for (int r = 0; r < 4; r++) {
        float y = acc[r] + bv;
        y = y > 0.f ? y : expm1f(y);
        ua[n][r] = y;
        ea[((size_t)g * EPG + w * 16 + lk * 4 + r) * 64 + col] = y;
      }
    }
  }
  __syncthreads();  // skip writes visible
  // ---- graph-LN + ELU: thread owns (n = t>>3, cols cg*8 per head) ----
  {
    const int n = t >> 3, cg = t & 7;
    float v16[16];
#pragma unroll
    for (int c = 0; c < 8; c++) {
      v16[c] = accH0[c] + el[n * XS + cg * 8 + c];
      v16[8 + c] = accH1[c] + el[n * XS + 64 + cg * 8 + c];
    }
    float s = 0.f, ss = 0.f;
#pragma unroll
    for (int j = 0; j < 16; j++) { s += v16[j]; ss += v16[j] * v16[j]; }
    for (int o2 = 32; o2 > 0; o2 >>= 1) { s += __shfl_down(s, o2); ss += __shfl_down(ss, o2); }
    if (lane == 0) { red0[w] = s; red1[w] = ss; }
    __syncthreads();
    if (t == 0) {
      float S = red0[0] + red0[1] + red0[2] + red0[3];
      float SS = red1[0] + red1[1] + red1[2] + red1[3];
      float mean = S / 4096.f;
      float var = SS / 4096.f - mean * mean;
      red0[0] = mean; red1[0] = rsqrtf(var + 1e-5f);
    }
    __syncthreads();
    float mean = red0[0], inv = red1[0];
    float* xg = xb + (size_t)g * NPG * HID;
#pragma unroll
    for (int hh = 0; hh < 2; hh++)
#pragma unroll
      for (int c = 0; c < 8; c++) {
        int col = hh * 64 + cg * 8 + c;
        float y = (v16[hh * 8 + c] - mean) * inv * lnw_[col] + lnb_[col];
        y = y > 0.f ? y : expm1f(y);
        xg[n * HID + col] = y;
        el[n * XS + col] = y;  // xnew for POOL
      }
  }

  if constexpr (POOL) {
    __syncthreads();  // xnew visible
    // P1: easum wave-partials + score
    {
#pragma unroll
      for (int n = 0; n < 4; n++) {
        float s = ua[n][0] + ua[n][1] + ua[n][2] + ua[n][3];
        s += __shfl_xor(s, 16);
        s += __shfl_xor(s, 32);
        if (lk == 0) qs2[w * 64 + n * 16 + l16] = s;
      }
      // score[n] = b_rel + agg[n]·w_rel + x[n]·w_root  (8 lanes/node, 16 cols each)
      const int n = t >> 3, part = t & 7;
      float s = 0.f;
      for (int c = part * 16; c < part * 16 + 16; c++)
        s += el[n * XS + c] * w_root[c];
      const int dg = deg_[n];
      for (int i = 0; i < dg; i++) {
        int sn = sl[lists[n * EPG + i]];
        for (int c = part * 16; c < part * 16 + 16; c++)
          s += el[sn * XS + c] * w_rel[c];
      }
      s += __shfl_xor(s, 1);
      s += __shfl_xor(s, 2);
      s += __shfl_xor(s, 4);
      if (part == 0) alE[n] = s + b_rel[0];
    }
    __syncthreads();
    // P2: easum combine (t<64) + score softmax (wave 2 lanes 0..31)
    if (t < 64)
      alE[64 + t] = qs2[t] + qs2[64 + t] + qs2[128 + t] + qs2[192 + t];
    if (t >= 128 && t < 160) {
      int n = t - 128;
      float sc = alE[n];
      float m = sc;
      for (int o2 = 1; o2 <= 16; o2 <<= 1) m = fmaxf(m, __shfl_xor(m, o2));
      float e = expf(sc - m);
      float su = e;
      for (int o2 = 1; o2 <= 16; o2 <<= 1) su += __shfl_xor(su, o2);
      alE[n] = e / (su + 1e-16f);
    }
    __syncthreads();
    // P3: g[ch] = sum_n score[n]*x[n][ch]; ge = ELU(easum@W_re+b_re); norm
    if (t < HID) {
      const int ch = t;
      float gv = 0.f;
      for (int n = 0; n < NPG; n++) gv += alE[n] * el[n * XS + ch];
      float s2 = b_re[ch];
      for (int k2 = 0; k2 < 64; k2++) s2 += alE[64 + k2] * W_re[k2 * HID + ch];
      s2 = s2 > 0.f ? s2 : expm1f(s2);
      float gl = gv * s2;
      el[4224 + ch] = gl;
      float sq = gl * gl;
      for (int o2 = 32; o2 > 0; o2 >>= 1) sq += __shfl_down(sq, o2);
      if (lane == 0) red0[w] = sq;
    }
    __syncthreads();
    if (t == 0) red1[0] = fmaxf(sqrtf(red0[0] + red0[1]), 1e-12f);
    __syncthreads();
    if (t < HID)
      outp[((size_t)g * NBLK + blk) * HID + t] = el[4224 + t] / red1[0];
  }
}

// ---------------- row LayerNorm over 128 channels ------------------------------------
__global__ void ln_row_kernel(const float* __restrict__ in, float* __restrict__ out,
                              const float* __restrict__ w, const float* __restrict__ b) {
  const int r = blockIdx.x, t = threadIdx.x;  // 128 threads
  float v = in[(size_t)r * HID + t];
  float s = v, ss = v * v;
  for (int off = 32; off > 0; off >>= 1) { s += __shfl_down(s, off); ss += __shfl_down(ss, off); }
  __shared__ float s0[2], s1[2];
  if ((t & 63) == 0) { s0[t >> 6] = s; s1[t >> 6] = ss; }
  __syncthreads();
  float S = s0[0] + s0[1], SS = s1[0] + s1[1];
  float mean = S / 128.f, var = SS / 128.f - mean * mean;
  out[(size_t)r * HID + t] = (v - mean) * rsqrtf(var + 1e-5f) * w[t] + b[t];
}

// ---------------- co-attention core: per (batch, head), seq-len 4 --------------------
__global__ void coattn_kernel(const float* __restrict__ qb, const float* __restrict__ kvb,
                              float* __restrict__ ob) {
  const int bh = blockIdx.x, b = bh >> 3, h = bh & 7, t = threadIdx.x;  // 64 threads
  __shared__ float attn[4][4];
  __shared__ float red[64];
  const int pair = t >> 2, part = t & 3;
  const int n = pair >> 2, m = pair & 3;
  const float* qp = qb + ((size_t)(b * 4 + n) * (CAH * CAD)) + h * CAD;
  const float* kp = kvb + ((size_t)(b * 4 + m) * (2 * CAH * CAD)) + h * CAD;
  float s = 0.f;
  for (int d = part * 32; d < part * 32 + 32; d++) s += qp[d] * kp[d];
  red[t] = s;
  __syncthreads();
  if (t < 16) {
    float sc = (red[t * 4] + red[t * 4 + 1] + red[t * 4 + 2] + red[t * 4 + 3]) * 0.08838834764831845f;
    attn[t >> 2][t & 3] = sc;
  }
  __syncthreads();
  if (t < 4) {
    float m_ = -1e30f;
    for (int j = 0; j < 4; j++) m_ = fmaxf(m_, attn[t][j]);
    float ex[4], su = 0.f;
    for (int j = 0; j < 4; j++) { ex[j] = expf(attn[t][j] - m_); su += ex[j]; }
    for (int j = 0; j < 4; j++) attn[t][j] = ex[j] / su;
  }
  __syncthreads();
  for (int i = t; i < 512; i += 64) {
    int n2 = i >> 7, d = i & 127;
    float acc = 0.f;
    for (int m2 = 0; m2 < 4; m2++)
      acc += attn[n2][m2] * kvb[((size_t)(b * 4 + m2) * (2 * CAH * CAD)) + CAH * CAD + h * CAD + d];
    ob[((size_t)(b * 4 + n2) * (CAH * CAD)) + h * CAD + d] = acc;
  }
}

// ---------------- final: m = ha . ta^T -> merge -> softmax ---------------------------
__global__ void final_kernel(const float* __restrict__ ha, const float* __restrict__ ta,
                             const float* __restrict__ Wm, const float* __restrict__ bm,
                             float* __restrict__ out) {
  const int b = blockIdx.x, t = threadIdx.x;  // 64 threads
  __shared__ float mm[16];
  if (t < 16) {
    int n = t >> 2, m2 = t & 3;
    const float* hp = ha + (size_t)(b * 4 + n) * HID;
    const float* tp = ta + (size_t)(b * 4 + m2) * HID;
    float s = 0.f;
    for (int c = 0; c < HID; c++) s += hp[c] * tp[c];
    mm[t] = s;
  }
  __syncthreads();
  if (t == 0) {
    float l0 = bm[0], l1 = bm[1];
    for (int j = 0; j < 16; j++) { l0 += mm[j] * Wm[j * 2]; l1 += mm[j] * Wm[j * 2 + 1]; }
    float m_ = fmaxf(l0, l1);
    float e0 = expf(l0 - m_), e1 = expf(l1 - m_);
    float su = e0 + e1;
    out[b * 2] = e0 / su;
    out[b * 2 + 1] = e1 / su;
  }
}

// ====================================================================================
extern "C" void kernel_launch(void* const* d_in, const int* in_sizes, int n_in,
                              void* d_out, int out_size, void* d_ws, size_t ws_size,
                              hipStream_t stream) {
  const float* xin[2]  = {(const float*)d_in[0], (const float*)d_in[1]};
  const float* eain[2] = {(const float*)d_in[2], (const float*)d_in[3]};
  const float* W_node = (const float*)d_in[4];
  const float* b_node = (const float*)d_in[5];
  const float* W_edge = (const float*)d_in[6];
  const float* b_edge = (const float*)d_in[7];
  const float* ln0_w = (const float*)d_in[8];
  const float* ln0_b = (const float*)d_in[9];
  const float* Wq = (const float*)d_in[10];
  const float* bq = (const float*)d_in[11];
  const float* Wk = (const float*)d_in[12];
  const float* bk = (const float*)d_in[13];
  const float* Wv = (const float*)d_in[14];
  const float* bv = (const float*)d_in[15];
  const float* We = (const float*)d_in[16];
  const float* Wskip = (const float*)d_in[17];
  const float* bs = (const float*)d_in[18];
  const float* Wup = (const float*)d_in[19];
  const float* bup = (const float*)d_in[20];
  const float* lnw = (const float*)d_in[21];
  const float* lnb = (const float*)d_in[22];
  const float* w_rel = (const float*)d_in[23];
  const float* b_rel = (const float*)d_in[24];
  const float* w_root = (const float*)d_in[25];
  const float* W_re = (const float*)d_in[26];
  const float* b_re = (const float*)d_in[27];
  const float* ca_lw = (const float*)d_in[28];
  const float* ca_lb = (const float*)d_in[29];
  const float* Wq_ca = (const float*)d_in[30];
  const float* Wkv_ca = (const float*)d_in[31];
  const float* Wo_ca = (const float*)d_in[32];
  const float* W_merge = (const float*)d_in[33];
  const float* b_merge = (const float*)d_in[34];
  const int* ei[2] = {(const int*)d_in[35], (const int*)d_in[36]};
  float* out = (float*)d_out;
  (void)in_sizes; (void)n_in; (void)out_size;

  char* base = (char*)d_ws;
  size_t off = 0;
  auto alloc = [&](size_t elems) {
    float* r = (float*)(base + off);
    off += ((elems * 4 + 255) & ~(size_t)255);
    return r;
  };
  auto allocb = [&](size_t elems) {  // bf16 elems
    ushortb* r = (ushortb*)(base + off);
    off += ((elems * 2 + 255) & ~(size_t)255);
    return r;
  };
  float* xb  = alloc((size_t)NNODE * HID);      // 32 MiB (also co-attn q buffer)
  float* ea  = alloc((size_t)NEDGE * 64);       // 32 MiB (also co-attn o buffer)
  float* big = alloc((size_t)8192 * 2048);      // 64 MiB (drug-2 xb/ea; later co-attn kv)
  float* hs  = alloc((size_t)NGRAPH * NBLK * HID);
  float* ts  = alloc((size_t)NGRAPH * NBLK * HID);
  float* rhn = alloc((size_t)NGRAPH * NBLK * HID);
  float* rtn = alloc((size_t)NGRAPH * NBLK * HID);
  float* hab = alloc((size_t)NGRAPH * NBLK * HID);
  float* tab = alloc((size_t)NGRAPH * NBLK * HID);
  ushortb* Wqkvh = allocb((size_t)8 * 384 * 128); ushortb* Wqkvl = allocb((size_t)8 * 384 * 128);
  ushortb* Wsh = allocb(8 * 16384);  ushortb* Wsl = allocb(8 * 16384);
  ushortb* Wuph = allocb(8 * 4096);  ushortb* Wupl = allocb(8 * 4096);
  ushortb* WeTh = allocb(8 * 8192);  ushortb* WeTl = allocb(8 * 8192);
  ushortb* Wqcah = allocb(131072);   ushortb* Wqcal = allocb(131072);
  ushortb* Wkvh = allocb(262144);    ushortb* Wkvl = allocb(262144);
  ushortb* Woh = allocb(131072);     ushortb* Wol = allocb(131072);
  float* bqkv = alloc(8 * 384);
  if (off > ws_size) return;  // diagnostic: fail with absmax, never fault

  float* xb2 = big;                          // drug-2 node state (32 MiB)
  float* ea2 = big + (size_t)NNODE * HID;    // drug-2 edge state (32 MiB)
  float* qc  = xb;   // co-attn aliases (xb/ea/big dead after main loop)
  float* kvc = big;
  float* oc  = ea;

  auto convw = [&](const float* s, ushortb* h, ushortb* l, int K, int N, int B,
                   int dstN, int nOff) {
    int tot = B * K * N;
    convw_kernel<<<(tot + 255) / 256, 256, 0, stream>>>(s, h, l, K, N, tot, dstN, nOff);
  };
  convw(Wq, Wqkvh, Wqkvl, 128, 128, 8, 384, 0);
  convw(Wk, Wqkvh, Wqkvl, 128, 128, 8, 384, 128);
  convw(Wv, Wqkvh, Wqkvl, 128, 128, 8, 384, 256);
  convw(Wskip, Wsh, Wsl, 128, 128, 8, 128, 0);
  convw(Wup, Wuph, Wupl, 64, 64, 8, 64, 0);
  convw(We, WeTh, WeTl, 64, 128, 8, 128, 0);
  convw(Wq_ca, Wqcah, Wqcal, 128, 1024, 1, 1024, 0);
  convw(Wkv_ca, Wkvh, Wkvl, 128, 2048, 1, 2048, 0);
  convw(Wo_ca, Woh, Wol, 1024, 128, 1, 128, 0);
  bcat_kernel<<<(8 * 384 + 255) / 256, 256, 0, stream>>>(bq, bk, bv, bqkv);

  // embeds for BOTH drugs
  run_gemm(xin[0], W_node, b_node, xb, NNODE, FINDIM, HID, false, stream);
  run_gemm(xin[1], W_node, b_node, xb2, NNODE, FINDIM, HID, false, stream);
  ln_graph_elu_kernel<<<NGRAPH, 256, 0, stream>>>(xb, xb, ln0_w, ln0_b);
  ln_graph_elu_kernel<<<NGRAPH, 256, 0, stream>>>(xb2, xb2, ln0_w, ln0_b);
  run_gemm(eain[0], W_edge, b_edge, ea, NEDGE, EINDIM, 64, true, stream);
  run_gemm(eain[1], W_edge, b_edge, ea2, NEDGE, EINDIM, 64, true, stream);

  // 8 batched mega launches (both drugs per launch)
  for (int i = 0; i < NBLK; ++i) {
    int pi0 = i * 2, pi1 = i * 2 + 1;
    mega_kernel<false><<<2 * NGRAPH, 256, 0, stream>>>(
        xb, ea, xb2, ea2,
        Wqkvh + (size_t)pi0 * 49152, Wqkvl + (size_t)pi0 * 49152,
        Wsh + (size_t)pi0 * 16384, Wsl + (size_t)pi0 * 16384,
        WeTh + (size_t)pi0 * 8192, WeTl + (size_t)pi0 * 8192,
        Wuph + (size_t)pi0 * 4096, Wupl + (size_t)pi0 * 4096,
        bqkv + pi0 * 384, bs + pi0 * 128, bup + pi0 * 64,
        lnw + pi0 * 128, lnb + pi0 * 128,
        w_rel, b_rel, w_root, W_re, b_re, nullptr, nullptr, 0,
        ei[0], ei[0] + NEDGE, ei[1], ei[1] + NEDGE);
    mega_kernel<true><<<2 * NGRAPH, 256, 0, stream>>>(
        xb, ea, xb2, ea2,
        Wqkvh + (size_t)pi1 * 49152, Wqkvl + (size_t)pi1 * 49152,
        Wsh + (size_t)pi1 * 16384, Wsl + (size_t)pi1 * 16384,
        WeTh + (size_t)pi1 * 8192, WeTl + (size_t)pi1 * 8192,
        Wuph + (size_t)pi1 * 4096, Wupl + (size_t)pi1 * 4096,
        bqkv + pi1 * 384, bs + pi1 * 128, bup + pi1 * 64,
        lnw + pi1 * 128, lnb + pi1 * 128,
        w_rel, b_rel, w_root, W_re, b_re, hs, ts, i,
        ei[0], ei[0] + NEDGE, ei[1], ei[1] + NEDGE);
  }

  ln_row_kernel<<<NGRAPH * NBLK, 128, 0, stream>>>(hs, rhn, ca_lw, ca_lb);
  ln_row_kernel<<<NGRAPH * NBLK, 128, 0, stream>>>(ts, rtn, ca_lw, ca_lb);
  // ha = coattn(q from rh, kv from rt)
  run_mf8(rhn, Wqcah, Wqcal, qc, NGRAPH * NBLK, 128, 1024, stream);
  run_mf8(rtn, Wkvh, Wkvl, kvc, NGRAPH * NBLK, 128, 2048, stream);
  coattn_kernel<<<NGRAPH * CAH, 64, 0, stream>>>(qc, kvc, oc);
  run_mf8(oc, Woh, Wol, hab, NGRAPH * NBLK, 1024, 128, stream);
  // ta = coattn(q from rt, kv from rh)
  run_mf8(rtn, Wqcah, Wqcal, qc, NGRAPH * NBLK, 128, 1024, stream);
  run_mf8(rhn, Wkvh, Wkvl, kvc, NGRAPH * NBLK, 128, 2048, stream);
  coattn_kernel<<<NGRAPH * CAH, 64, 0, stream>>>(qc, kvc, oc);
  run_mf8(oc, Woh, Wol, tab, NGRAPH * NBLK, 1024, 128, stream);

  final_kernel<<<NGRAPH, 64, 0, stream>>>(hab, tab, W_merge, b_merge, out);
}